// Round 5
// baseline (73.414 us; speedup 1.0000x reference)
//
#include <hip/hip_runtime.h>
#include <math.h>

#define BB 32
#define CC 256
#define HH 64
#define WW 64
#define HWSZ 4096              // HH*WW
#define CHW 1048576            // CC*HWSZ

typedef float f4 __attribute__((ext_vector_type(4)));   // native vec4 for nt-store

// ---------------------------------------------------------------------------
// Kernel A: channel-wise max + mean over C=256 for each (b, spatial).
// One block per (b, h) row: 2048 blocks -> 8 blocks/CU -> full occupancy.
// 256 threads = 16 channel-groups x 16 float4 spatial lanes; each thread
// reduces 16 channels (fully unrolled float4 loads), then LDS combine.
// ---------------------------------------------------------------------------
__global__ void sg_reduce(const float* __restrict__ x,
                          float* __restrict__ maxp,
                          float* __restrict__ meanp) {
    int bh = blockIdx.x;                 // b*64 + h
    int b  = bh >> 6;
    int h  = bh & 63;
    int w4 = threadIdx.x & 15;           // 16 float4 per 64-wide row
    int cg = threadIdx.x >> 4;           // 16 channel groups of 16

    const f4* base =
        reinterpret_cast<const f4*>(x + (size_t)b * CHW + h * WW) + w4;
    // channel stride in float4 units: HWSZ/4 = 1024
    f4 v = base[(size_t)(cg * 16) * 1024];
    f4 mx = v, sm = v;
    #pragma unroll
    for (int cc = 1; cc < 16; ++cc) {
        f4 u = base[(size_t)(cg * 16 + cc) * 1024];
        mx.x = fmaxf(mx.x, u.x); mx.y = fmaxf(mx.y, u.y);
        mx.z = fmaxf(mx.z, u.z); mx.w = fmaxf(mx.w, u.w);
        sm += u;
    }

    __shared__ f4 lmax[16][16];
    __shared__ f4 lsum[16][16];
    lmax[cg][w4] = mx;
    lsum[cg][w4] = sm;
    __syncthreads();

    if (threadIdx.x < 16) {
        int w = threadIdx.x;
        f4 M = lmax[0][w];
        f4 S = lsum[0][w];
        #pragma unroll
        for (int g = 1; g < 16; ++g) {
            f4 m2 = lmax[g][w];
            S += lsum[g][w];
            M.x = fmaxf(M.x, m2.x); M.y = fmaxf(M.y, m2.y);
            M.z = fmaxf(M.z, m2.z); M.w = fmaxf(M.w, m2.w);
        }
        reinterpret_cast<f4*>(maxp)[bh * 16 + w] = M;
        reinterpret_cast<f4*>(meanp)[bh * 16 + w] = S * (1.0f / CC);
    }
}

// ---------------------------------------------------------------------------
// Kernel B: 7x7 conv (2 in-ch -> 1 out-ch, same padding) + sigmoid -> scale.
// One thread per (b,h,w); 512 blocks, ~2.5 us. Planes (1 MB) are L2-resident.
// ---------------------------------------------------------------------------
__global__ void sg_conv(const float* __restrict__ maxp,
                        const float* __restrict__ meanp,
                        const float* __restrict__ Wt,
                        float* __restrict__ scale) {
    __shared__ float w[98];
    int lt = threadIdx.x;
    if (lt < 98) w[lt] = Wt[lt];
    __syncthreads();

    int t = blockIdx.x * blockDim.x + lt;            // < BB*HWSZ = 131072
    int b = t >> 12;
    int s = t & 4095;
    int h = s >> 6;
    int wc = s & 63;
    const float* mb = maxp  + b * HWSZ;
    const float* nb = meanp + b * HWSZ;

    float acc = 0.0f;
    #pragma unroll
    for (int kh = 0; kh < 7; ++kh) {
        int hh = h + kh - 3;
        if ((unsigned)hh >= (unsigned)HH) continue;
        #pragma unroll
        for (int kw = 0; kw < 7; ++kw) {
            int wcol = wc + kw - 3;
            if ((unsigned)wcol >= (unsigned)WW) continue;
            int o = (hh << 6) + wcol;
            acc = fmaf(mb[o], w[kh * 7 + kw],      acc);
            acc = fmaf(nb[o], w[49 + kh * 7 + kw], acc);
        }
    }
    scale[t] = 1.0f / (1.0f + __expf(-acc));
}

// ---------------------------------------------------------------------------
// Kernel C: pure streaming apply, no sync, no prologue.
// One block per (b,h) row; 256 thr = 16 channel-groups x 16 f4 lanes.
// scale f4 read once per thread (0.5 MB plane, L2-resident), then 16
// unrolled {load x, multiply, nt-store out} pairs at full MLP.
// ---------------------------------------------------------------------------
__global__ void __launch_bounds__(256, 8)
sg_apply(const float* __restrict__ x,
         const float* __restrict__ scale,
         float* __restrict__ out) {
    int bh = blockIdx.x;                 // b*64 + h
    int b  = bh >> 6;
    int h  = bh & 63;
    int w4 = threadIdx.x & 15;
    int cg = threadIdx.x >> 4;

    f4 sc = reinterpret_cast<const f4*>(scale)[bh * 16 + w4];

    const f4* xb =
        reinterpret_cast<const f4*>(x + (size_t)b * CHW + h * WW) + w4;
    f4* ob =
        reinterpret_cast<f4*>(out + (size_t)b * CHW + h * WW) + w4;

    #pragma unroll
    for (int cc = 0; cc < 16; ++cc) {
        size_t off = (size_t)(cg * 16 + cc) * 1024;   // channel stride (f4)
        f4 v = xb[off];
        v *= sc;
        __builtin_nontemporal_store(v, ob + off);
    }
}

extern "C" void kernel_launch(void* const* d_in, const int* in_sizes, int n_in,
                              void* d_out, int out_size, void* d_ws, size_t ws_size,
                              hipStream_t stream) {
    const float* x  = (const float*)d_in[0];   // [32,256,64,64]
    const float* Wt = (const float*)d_in[1];   // [1,2,7,7] = 98 floats
    float* out = (float*)d_out;

    float* wsf   = (float*)d_ws;
    float* maxp  = wsf;                        // 131072 floats
    float* meanp = wsf + BB * HWSZ;            // 131072 floats
    float* scale = wsf + 2 * BB * HWSZ;        // 131072 floats

    // A: reduce over channels (one block per (b,h) row)
    sg_reduce<<<BB * HH, 256, 0, stream>>>(x, maxp, meanp);
    // B: conv + sigmoid -> scale plane
    sg_conv<<<(BB * HWSZ) / 256, 256, 0, stream>>>(maxp, meanp, Wt, scale);
    // C: pure streaming apply
    sg_apply<<<BB * HH, 256, 0, stream>>>(x, scale, out);
}